// Round 3
// baseline (301.155 us; speedup 1.0000x reference)
//
#include <hip/hip_runtime.h>

#define NWIN 1000
#define WIN  500
#define HID  30
#define ANC  7
#define BATCH 64
#define KS   75
#define PADH 37
#define OBASE_ELEMS (BATCH*ANC*NWIN*2)   // 896000

// ---------------------------------------------------------------------------
// Kernel 1 (v3): no LDS / no barriers in the main loop.
//   wave = (bhalf, khalf); lane = (bloc in 0..31, c in 0..1)
//   each lane: acc[30] = partial h[b][j][c] over its K-half
//   x: per-lane contiguous global loads, register double-buffered
//   W1: wave-uniform -> scalar loads (SGPR), no LDS broadcast traffic
//   epilogue: K-reduce via LDS, batchnorm butterfly, GEMM2, write out_base
// ---------------------------------------------------------------------------
__global__ __launch_bounds__(256, 4) void k1(
        const float* __restrict__ x,
        const float* __restrict__ W1, const float* __restrict__ b1,
        const float* __restrict__ W2, const float* __restrict__ b2,
        float* __restrict__ out_base)
{
    __shared__ float hsh2[2][64][61];   // [khalf][b][c*30+j], stride 61 (odd)

    const int n    = blockIdx.x;
    const int t    = threadIdx.x;
    const int wid  = __builtin_amdgcn_readfirstlane(t >> 6);
    const int lane = t & 63;
    const int khalf = wid & 1;
    const int bhalf = wid >> 1;
    const int bloc  = lane & 31;
    const int cc    = lane >> 5;
    const int b     = bhalf * 32 + bloc;

    // lane's x stream: floats (n*1000 + k*100 + khalf*50 + wl*2 + cc)
    const float* __restrict__ xb = x + (size_t)b * 1000000u + (size_t)n * 1000u
                                     + khalf * 50 + cc;
    // wave-uniform W stream: W1[n][w][j], w = k*50 + khalf*25 + wl
    const float* __restrict__ wbase = W1 + (size_t)n * 15000u + khalf * 750;

    float acc[30];
#pragma unroll
    for (int j = 0; j < 30; ++j) acc[j] = 0.f;

    float xA[25], xB[25];
#pragma unroll
    for (int wl = 0; wl < 25; ++wl) xA[wl] = xb[wl * 2];

#define K1_COMPUTE(XC, K) {                                        \
    const float* __restrict__ wk = wbase + (size_t)(K) * 1500;     \
    _Pragma("unroll") for (int wl = 0; wl < 25; ++wl) {            \
        const float xv = fmaf(2.f, XC[wl], -1.f);                  \
        _Pragma("unroll") for (int j = 0; j < 30; ++j)             \
            acc[j] = fmaf(xv, wk[wl * 30 + j], acc[j]);            \
    } }

#define K1_LOAD(XN, K) {                                           \
    const float* __restrict__ xp = xb + (size_t)(K) * 100;         \
    _Pragma("unroll") for (int wl = 0; wl < 25; ++wl)              \
        XN[wl] = xp[wl * 2];                                       \
    }

    for (int kk = 0; kk < 5; ++kk) {
        const int k0 = 2 * kk;
        K1_LOAD(xB, k0 + 1);         // prefetch next chunk (independent regs)
        K1_COMPUTE(xA, k0);
        if (kk < 4) K1_LOAD(xA, k0 + 2);
        K1_COMPUTE(xB, k0 + 1);
    }
#undef K1_COMPUTE
#undef K1_LOAD

    // ---- K-reduce partials via LDS ----
#pragma unroll
    for (int j = 0; j < 30; ++j)
        hsh2[khalf][b][cc * 30 + j] = acc[j];
    __syncthreads();

    // ---- bias + relu + batch stats (64-lane butterfly) + normalize ----
    {
        const int bb = t & 63;
        const int q2 = t >> 6;
        const int ch = q2 >> 1;          // channel
        const int jh = (q2 & 1) * 15;    // j-half
        const float* __restrict__ b1p = b1 + n * HID + jh;
#pragma unroll
        for (int jj = 0; jj < 15; ++jj) {
            const int col = ch * 30 + jh + jj;
            float v = hsh2[0][bb][col] + hsh2[1][bb][col] + b1p[jj];
            v = fmaxf(v, 0.f);
            float s = v, ss = v * v;
#pragma unroll
            for (int off = 32; off > 0; off >>= 1) {
                s  += __shfl_xor(s, off);
                ss += __shfl_xor(ss, off);
            }
            const float mean = s * (1.f / 64.f);
            const float var  = ss * (1.f / 64.f) - mean * mean;
            const float rn   = rsqrtf(var + 1e-5f);
            hsh2[0][bb][col] = (v - mean) * rn;
        }
    }
    __syncthreads();

    // ---- GEMM2: o[b,a,c] = b2[n,a] + sum_h hsh2[0][b][c*30+h] * W2[n,h,a] ----
    const float* __restrict__ w2p = W2 + (size_t)n * (HID * ANC);
    for (int idx = t; idx < BATCH * ANC * 2; idx += 256) {
        const int bb = idx / 14;
        const int r  = idx % 14;
        const int a  = r >> 1, c = r & 1;
        float o = b2[n * ANC + a];
        const float* hp = &hsh2[0][bb][c * 30];
#pragma unroll
        for (int h = 0; h < HID; ++h)
            o = fmaf(hp[h], w2p[h * ANC + a], o);
        out_base[(((size_t)bb * ANC + a) * NWIN + n) * 2 + c] = o;
    }
}

// ---------------------------------------------------------------------------
// Kernel 2: softmax over ANC + reflect-pad + conv (2 needed output columns)
// via sum/diff factorization (unchanged — ~13us, VALU-bound).
// ---------------------------------------------------------------------------
__global__ __launch_bounds__(256, 2) void k2(
        const float* __restrict__ out_base,
        const float* __restrict__ conv_w, const float* __restrict__ conv_b,
        float* __restrict__ out_smooth)
{
    __shared__ float2 sdl[199 * ANC];       // {S,D} per (row, i)
    __shared__ float2 wael[ANC * ANC * KS]; // {A,E} per (o, i, kh)

    const int bidx = blockIdx.x;
    const int b  = bidx >> 3;
    const int ht = bidx & 7;
    const int h0 = ht * 125;
    const int t  = threadIdx.x;

    const float2* __restrict__ cw2 = reinterpret_cast<const float2*>(conv_w);
    for (int idx = t; idx < ANC * ANC * KS; idx += 256) {
        const float2 w = cw2[idx];
        wael[idx] = make_float2(w.x + w.y, w.x - w.y);
    }

    if (t < 199) {
        const int hglob = h0 - PADH + t;
        const int hm = hglob < 0 ? -hglob
                     : (hglob >= NWIN ? 2 * NWIN - 2 - hglob : hglob);
        float p[2][ANC];
#pragma unroll
        for (int c = 0; c < 2; ++c) {
            float v[ANC];
            float m = -1e30f;
#pragma unroll
            for (int a = 0; a < ANC; ++a) {
                v[a] = out_base[(((size_t)b * ANC + a) * NWIN + hm) * 2 + c];
                m = fmaxf(m, v[a]);
            }
            float s = 0.f;
#pragma unroll
            for (int a = 0; a < ANC; ++a) { v[a] = __expf(v[a] - m); s += v[a]; }
            const float inv = 1.f / s;
#pragma unroll
            for (int a = 0; a < ANC; ++a) p[c][a] = v[a] * inv;
        }
#pragma unroll
        for (int a = 0; a < ANC; ++a)
            sdl[t * ANC + a] = make_float2(p[0][a] + p[1][a], p[0][a] - p[1][a]);
    }
    __syncthreads();

    for (int idx = t; idx < ANC * 125; idx += 256) {
        const int o  = idx / 125;
        const int hl = idx % 125;
        float sa = 0.f, de = 0.f;
        const float2* __restrict__ wrow = &wael[o * ANC * KS];
#pragma unroll 1
        for (int i = 0; i < ANC; ++i) {
            const float2* __restrict__ sdp = &sdl[hl * ANC + i];
            const float2* __restrict__ wp  = &wrow[i * KS];
#pragma unroll 5
            for (int kh = 0; kh < KS; ++kh) {
                const float2 sd = sdp[kh * ANC];
                const float2 we = wp[kh];
                sa = fmaf(sd.x, we.x, sa);
                de = fmaf(sd.y, we.y, de);
            }
        }
        const float cb = conv_b[o];
        const float o0 = 0.5f * (sa - de) + cb;
        const float o1 = 0.5f * (sa + de) + cb;
        const size_t base = (((size_t)b * ANC + o) * NWIN + (h0 + hl)) * 2;
        out_smooth[base + 0] = o0;
        out_smooth[base + 1] = o1;
    }
}

extern "C" void kernel_launch(void* const* d_in, const int* in_sizes, int n_in,
                              void* d_out, int out_size, void* d_ws, size_t ws_size,
                              hipStream_t stream)
{
    const float* x      = (const float*)d_in[0];
    const float* W1     = (const float*)d_in[1];
    const float* b1     = (const float*)d_in[2];
    const float* W2     = (const float*)d_in[3];
    const float* b2     = (const float*)d_in[4];
    const float* conv_w = (const float*)d_in[5];
    const float* conv_b = (const float*)d_in[6];
    float* out = (float*)d_out;

    k1<<<dim3(NWIN), dim3(256), 0, stream>>>(x, W1, b1, W2, b2, out);
    k2<<<dim3(BATCH * 8), dim3(256), 0, stream>>>(out, conv_w, conv_b,
                                                  out + OBASE_ELEMS);
}

// Round 4
// 202.944 us; speedup vs baseline: 1.4839x; 1.4839x over previous
//
#include <hip/hip_runtime.h>

#define NWIN 1000
#define WIN  500
#define HID  30
#define ANC  7
#define BATCH 64
#define KS   75
#define PADH 37
#define OBASE_ELEMS (BATCH*ANC*NWIN*2)   // 896000

// k1 geometry: 20 chunks of 25 w-positions
#define CK_W   25
#define NCK    20

// LDS float-offset map (one flat array, epilogue overlays the front)
//   xs[buf][c][b][28] : ((buf*2+c)*64+b)*28 + q          [0 .. 7167]
//   ws[buf][25][32]   : 7168 + buf*800 + w*32 + j        [7168 .. 8767]
//   hs[wh][b][61]     : (wh*64+b)*61 + col   (overlay)   [0 .. 7807]
#define XS(buf,c,b,q) ((((buf)*2+(c))*64+(b))*28 + (q))
#define WSO(buf,w,j)  (7168 + (buf)*800 + (w)*32 + (j))
#define HS(wh,b,col)  (((wh)*64+(b))*61 + (col))

__device__ __forceinline__ void gload_lds16(const float* g, float* l) {
    __builtin_amdgcn_global_load_lds(
        (const __attribute__((address_space(1))) void*)g,
        (__attribute__((address_space(3))) void*)l, 16, 0, 0);
}

// ---------------------------------------------------------------------------
// Kernel 1 (v4): one block per window. 4 waves = (bhalf, whalf).
// lane = (bloc 0..31, c 0..1); each lane accumulates all 30 h for one (b,c)
// over its wave's w-subset. W1 staged via global_load_lds into padded [w][32]
// (pre-swizzled source); x reg-staged as float2 (12-14 VGPR, sched-pinned)
// into stride-28 conflict-free layout. Double-buffered, 1 barrier/chunk.
// ---------------------------------------------------------------------------
__global__ __launch_bounds__(256, 4) void k1(
        const float* __restrict__ x,
        const float* __restrict__ W1, const float* __restrict__ b1,
        const float* __restrict__ W2, const float* __restrict__ b2,
        float* __restrict__ out_base)
{
    __shared__ float smem[8768];   // 35,072 B -> 4 blocks/CU

    const int n    = blockIdx.x;
    const int t    = threadIdx.x;
    const int wid  = __builtin_amdgcn_readfirstlane(t >> 6);
    const int lane = t & 63;
    const int wh   = wid & 1;          // w-half of each chunk
    const int bh   = wid >> 1;         // batch half
    const int bloc = lane & 31;
    const int cc   = lane >> 5;
    const int b    = bh * 32 + bloc;
    const int wh12 = wh * 12;

    float acc[30];
#pragma unroll
    for (int j = 0; j < 30; ++j) acc[j] = 0.f;

    float2 xr[7];

    // ---- stage-issue helpers -------------------------------------------
    const float2* __restrict__ x2 = reinterpret_cast<const float2*>(x);

    auto issue_x = [&](int ck) {
        const size_t base = (size_t)n * 500 + (size_t)ck * 25;
#pragma unroll
        for (int r = 0; r < 6; ++r) {
            const int g  = t + r * 256;          // 0..1535
            const int bb = g / 25, q = g - bb * 25;
            xr[r] = x2[(size_t)bb * 500000 + base + q];
        }
        if (t < 64) {
            const int g  = t + 1536;             // 1536..1599
            const int bb = g / 25, q = g - bb * 25;
            xr[6] = x2[(size_t)bb * 500000 + base + q];
        }
    };

    auto commit_x = [&](int buf) {
#pragma unroll
        for (int r = 0; r < 6; ++r) {
            const int g  = t + r * 256;
            const int bb = g / 25, q = g - bb * 25;
            smem[XS(buf, 0, bb, q)] = xr[r].x;
            smem[XS(buf, 1, bb, q)] = xr[r].y;
        }
        if (t < 64) {
            const int g  = t + 1536;
            const int bb = g / 25, q = g - bb * 25;
            smem[XS(buf, 0, bb, q)] = xr[6].x;
            smem[XS(buf, 1, bb, q)] = xr[6].y;
        }
    };

    // W chunk: 25 rows * 30 floats packed -> 200 16B granules into padded
    // [25][32]; source granule (w, k): floats w*30 + 4k (straddle -> pad junk)
    auto issue_w = [&](int ck, int buf) {
        if (t < 200) {
            const int w  = t >> 3, kq = t & 7;
            size_t off = (size_t)n * 15000 + (size_t)ck * 750 + w * 30 + kq * 4;
            if (off > 14999996u) off = 14999996u;          // clamp tail OOB
            gload_lds16(W1 + off, &smem[7168 + buf * 800 + (t & 192) * 4]);
        }
    };

    // ---- 30-FMA inner body ---------------------------------------------
    auto dot30 = [&](float xcomp, const float4* __restrict__ wrow) {
        const float xv = fmaf(2.f, xcomp, -1.f);
        float4 w8[8];
#pragma unroll
        for (int u = 0; u < 8; ++u) w8[u] = wrow[u];
#pragma unroll
        for (int j = 0; j < 30; ++j) {
            const float wv = ((const float*)&w8[j >> 2])[j & 3];
            acc[j] = fmaf(xv, wv, acc[j]);
        }
    };

    // ---- prologue: stage chunk 0 ---------------------------------------
    issue_w(0, 0);
    issue_x(0);
    commit_x(0);
    __syncthreads();

    // ---- main loop: 1 barrier per chunk, double-buffered ---------------
    for (int ck = 0; ck < NCK; ++ck) {
        const int cur = ck & 1, nxt = cur ^ 1;
        const bool pre = (ck < NCK - 1);
        if (pre) {
            issue_w(ck + 1, nxt);
            issue_x(ck + 1);
            __builtin_amdgcn_sched_barrier(0);   // pin issues before compute
        }

        const float* __restrict__ xrow = &smem[XS(cur, cc, b, wh12)];
        const float4* __restrict__ wp  =
            reinterpret_cast<const float4*>(&smem[WSO(cur, wh12, 0)]);
        const float4* __restrict__ xr4 = reinterpret_cast<const float4*>(xrow);

#pragma unroll
        for (int g = 0; g < 3; ++g) {
            const float4 xq = xr4[g];
            dot30(xq.x, wp + (g * 4 + 0) * 8);
            dot30(xq.y, wp + (g * 4 + 1) * 8);
            dot30(xq.z, wp + (g * 4 + 2) * 8);
            dot30(xq.w, wp + (g * 4 + 3) * 8);
        }
        if (wh12) dot30(xrow[12], wp + 96);      // 13th position of upper half

        if (pre) commit_x(nxt);                  // vmcnt waits land here
        __syncthreads();                         // drains gload_lds too
    }

    // ---- epilogue: reduce whalf partials (overlay region) --------------
#pragma unroll
    for (int j = 0; j < 30; ++j)
        smem[HS(wh, b, cc * 30 + j)] = acc[j];
    __syncthreads();

    {   // bias + relu + batch stats (64-lane butterfly) + normalize
        const int bb = t & 63;
        const int q2 = t >> 6;
        const int ch = q2 >> 1;
        const int jh = (q2 & 1) * 15;
        const float* __restrict__ b1p = b1 + n * HID + jh;
#pragma unroll
        for (int jj = 0; jj < 15; ++jj) {
            const int col = ch * 30 + jh + jj;
            float v = smem[HS(0, bb, col)] + smem[HS(1, bb, col)] + b1p[jj];
            v = fmaxf(v, 0.f);
            float s = v, ss = v * v;
#pragma unroll
            for (int off = 32; off > 0; off >>= 1) {
                s  += __shfl_xor(s, off);
                ss += __shfl_xor(ss, off);
            }
            const float mean = s * (1.f / 64.f);
            const float var  = ss * (1.f / 64.f) - mean * mean;
            const float rn   = rsqrtf(var + 1e-5f);
            smem[HS(0, bb, col)] = (v - mean) * rn;
        }
    }
    __syncthreads();

    // ---- GEMM2 + write out_base[b][a][n][c] (float2 per (b,a)) ---------
    const float* __restrict__ w2p = W2 + (size_t)n * (HID * ANC);
    float2* __restrict__ ob2 = reinterpret_cast<float2*>(out_base);
    for (int idx = t; idx < BATCH * ANC; idx += 256) {
        const int bb = idx / 7, a = idx - bb * 7;
        float o0 = b2[n * ANC + a], o1 = o0;
#pragma unroll
        for (int h = 0; h < HID; ++h) {
            const float wv = w2p[h * ANC + a];
            o0 = fmaf(smem[HS(0, bb, h)],      wv, o0);
            o1 = fmaf(smem[HS(0, bb, 30 + h)], wv, o1);
        }
        ob2[((size_t)bb * ANC + a) * NWIN + n] = make_float2(o0, o1);
    }
}

// ---------------------------------------------------------------------------
// Kernel 2: softmax over ANC + reflect-pad + conv (2 needed output columns)
// via sum/diff factorization (unchanged).
// ---------------------------------------------------------------------------
__global__ __launch_bounds__(256, 2) void k2(
        const float* __restrict__ out_base,
        const float* __restrict__ conv_w, const float* __restrict__ conv_b,
        float* __restrict__ out_smooth)
{
    __shared__ float2 sdl[199 * ANC];
    __shared__ float2 wael[ANC * ANC * KS];

    const int bidx = blockIdx.x;
    const int b  = bidx >> 3;
    const int ht = bidx & 7;
    const int h0 = ht * 125;
    const int t  = threadIdx.x;

    const float2* __restrict__ cw2 = reinterpret_cast<const float2*>(conv_w);
    for (int idx = t; idx < ANC * ANC * KS; idx += 256) {
        const float2 w = cw2[idx];
        wael[idx] = make_float2(w.x + w.y, w.x - w.y);
    }

    if (t < 199) {
        const int hglob = h0 - PADH + t;
        const int hm = hglob < 0 ? -hglob
                     : (hglob >= NWIN ? 2 * NWIN - 2 - hglob : hglob);
        float p[2][ANC];
#pragma unroll
        for (int c = 0; c < 2; ++c) {
            float v[ANC];
            float m = -1e30f;
#pragma unroll
            for (int a = 0; a < ANC; ++a) {
                v[a] = out_base[(((size_t)b * ANC + a) * NWIN + hm) * 2 + c];
                m = fmaxf(m, v[a]);
            }
            float s = 0.f;
#pragma unroll
            for (int a = 0; a < ANC; ++a) { v[a] = __expf(v[a] - m); s += v[a]; }
            const float inv = 1.f / s;
#pragma unroll
            for (int a = 0; a < ANC; ++a) p[c][a] = v[a] * inv;
        }
#pragma unroll
        for (int a = 0; a < ANC; ++a)
            sdl[t * ANC + a] = make_float2(p[0][a] + p[1][a], p[0][a] - p[1][a]);
    }
    __syncthreads();

    for (int idx = t; idx < ANC * 125; idx += 256) {
        const int o  = idx / 125;
        const int hl = idx % 125;
        float sa = 0.f, de = 0.f;
        const float2* __restrict__ wrow = &wael[o * ANC * KS];
#pragma unroll 1
        for (int i = 0; i < ANC; ++i) {
            const float2* __restrict__ sdp = &sdl[hl * ANC + i];
            const float2* __restrict__ wp  = &wrow[i * KS];
#pragma unroll 5
            for (int kh = 0; kh < KS; ++kh) {
                const float2 sd = sdp[kh * ANC];
                const float2 we = wp[kh];
                sa = fmaf(sd.x, we.x, sa);
                de = fmaf(sd.y, we.y, de);
            }
        }
        const float cb = conv_b[o];
        const float o0 = 0.5f * (sa - de) + cb;
        const float o1 = 0.5f * (sa + de) + cb;
        const size_t base = (((size_t)b * ANC + o) * NWIN + (h0 + hl)) * 2;
        out_smooth[base + 0] = o0;
        out_smooth[base + 1] = o1;
    }
}

extern "C" void kernel_launch(void* const* d_in, const int* in_sizes, int n_in,
                              void* d_out, int out_size, void* d_ws, size_t ws_size,
                              hipStream_t stream)
{
    const float* x      = (const float*)d_in[0];
    const float* W1     = (const float*)d_in[1];
    const float* b1     = (const float*)d_in[2];
    const float* W2     = (const float*)d_in[3];
    const float* b2     = (const float*)d_in[4];
    const float* conv_w = (const float*)d_in[5];
    const float* conv_b = (const float*)d_in[6];
    float* out = (float*)d_out;

    k1<<<dim3(NWIN), dim3(256), 0, stream>>>(x, W1, b1, W2, b2, out);
    k2<<<dim3(BATCH * 8), dim3(256), 0, stream>>>(out, conv_w, conv_b,
                                                  out + OBASE_ELEMS);
}